// Round 11
// baseline (125.117 us; speedup 1.0000x reference)
//
#include <hip/hip_runtime.h>

#define T_FRAMES 16384
#define N_MELS 128
#define N_FREQ 513
#define FPB 16             // frames per block
#define BT 256             // 4 waves
#define LOG2_10 3.3219280948873623f

typedef short bf16x8 __attribute__((ext_vector_type(8)));
typedef unsigned short u16x8 __attribute__((ext_vector_type(8)));
typedef float f32x4 __attribute__((ext_vector_type(4)));

__device__ __forceinline__ unsigned short f2bf(float x) {
  unsigned u = __float_as_uint(x);
  return (unsigned short)((u + 0x7FFFu + ((u >> 16) & 1u)) >> 16);
}
__device__ __forceinline__ float bf2f(unsigned short h) {
  return __uint_as_float(((unsigned)h) << 16);
}

// ---- Kernel 0: build frag-ready bf16 hi/lo image of B (unchanged) -------
// gid bits [w8:3][ft:2][ks:2][hl:1][l:6]; lane l of frag (w8,ft,ks,hl) holds
// B[f][k0..k0+8) bf16, f = w8*64+ft*16+(l&15), k0 = ks*32+(l>>4)*8.
__global__ __launch_bounds__(256) void build_bimg(
    const float* __restrict__ B, unsigned short* __restrict__ img) {
  int gid = blockIdx.x * 256 + threadIdx.x;   // 0..16383
  int l  = gid & 63;
  int hl = (gid >> 6) & 1;
  int ks = (gid >> 7) & 3;
  int ft = (gid >> 9) & 3;
  int w  = gid >> 11;
  int f  = w * 64 + ft * 16 + (l & 15);
  int k0 = ks * 32 + (l >> 4) * 8;
  const float* src = B + f * N_MELS + k0;
  u16x8 o;
#pragma unroll
  for (int j = 0; j < 8; ++j) {
    float x = src[j];
    unsigned short hi = f2bf(x);
    o[j] = hl ? f2bf(x - bf2f(hi)) : hi;
  }
  *((u16x8*)img + gid) = o;
}

// ---- Kernel A: fused MFMA GEMM + cos transform + Levinson + expand ------
// 4 waves/block, 16 frames/block, 1024 blocks -> 4 blocks/CU.
__global__ __launch_bounds__(BT, 4) void mel2lpc_mfma(
    const float* __restrict__ mel,   // [128][16384]
    const float* __restrict__ B,     // [513][128] (row 512 only)
    const float* __restrict__ lag,   // [5]
    const unsigned short* __restrict__ bimg,
    float* __restrict__ out)         // [4][16384*256]
{
  __shared__ float X16T[FPB][132];              // 8.4 KB (pad 132: 2-way free)
  __shared__ __align__(16) short Xf[8][512];    // 8 KB: frags (ks,hl)
  __shared__ float W_s[5][N_FREQ];              // 10.3 KB
  __shared__ float red[4][5][FPB];              // 1.25 KB
  __shared__ float lp[4][FPB];                  // 256 B
  __shared__ float pv512[FPB];                  // 64 B

  const int tid = threadIdx.x;
  const int lane = tid & 63;
  const int wv = __builtin_amdgcn_readfirstlane(tid >> 6);   // 0..3
  const int t0 = blockIdx.x * FPB;

  // ---- Phase 0: issue mel loads FIRST (hide HBM latency under W build) ----
  float mv[8];
#pragma unroll
  for (int r = 0; r < 8; ++r) {
    int idx = r * BT + tid;    // 0..2047
    int t = idx & 15;
    int m = idx >> 4;
    mv[r] = mel[m * T_FRAMES + t0 + t];
  }
  float la0 = lag[0], la1 = lag[1], la2 = lag[2], la3 = lag[3], la4 = lag[4];
  // W[k][f] = lag[k]*cf*cos(2*pi*k*f/1024)
  for (int f = tid; f < N_FREQ; f += BT) {
    float cf = (f == 0 || f == N_FREQ - 1) ? (1.0f / 1024.0f) : (2.0f / 1024.0f);
    float ang = (float)f * (1.0f / 512.0f);
    W_s[0][f] = la0 * cf;
    W_s[1][f] = la1 * cf * cospif(ang);
    W_s[2][f] = la2 * cf * cospif(2.0f * ang);
    W_s[3][f] = la3 * cf * cospif(3.0f * ang);
    W_s[4][f] = la4 * cf * cospif(4.0f * ang);
  }
#pragma unroll
  for (int r = 0; r < 8; ++r) {
    int idx = r * BT + tid;
    int t = idx & 15;
    int m = idx >> 4;
    X16T[t][m] = exp2f(mv[r] * LOG2_10);
  }
  __syncthreads();

  // ---- Phase 1: frag build (wave wv = ks slice wv) + f=512 row ----
  {
    int t = lane & 15;
    int k0 = wv * 32 + (lane >> 4) * 8;
    float4 a0 = *(const float4*)&X16T[t][k0];
    float4 a1 = *(const float4*)&X16T[t][k0 + 4];
    float xs[8] = {a0.x, a0.y, a0.z, a0.w, a1.x, a1.y, a1.z, a1.w};
    u16x8 vh, vl;
#pragma unroll
    for (int j = 0; j < 8; ++j) {
      unsigned short hi = f2bf(xs[j]);
      vh[j] = hi;
      vl[j] = f2bf(xs[j] - bf2f(hi));
    }
    *(u16x8*)&Xf[wv * 2][lane * 8] = vh;
    *(u16x8*)&Xf[wv * 2 + 1][lane * 8] = vl;
  }
  if (wv == 0 && lane < FPB) {   // f=512 row power
    const int t = lane;
    float s = 0.f;
    const float4* __restrict__ B512 = (const float4*)(B + 512 * N_MELS);
#pragma unroll
    for (int mi = 0; mi < 32; ++mi) {
      float4 b = B512[mi];
      float4 xv = *(const float4*)&X16T[t][mi * 4];
      s = fmaf(b.x, xv.x, s); s = fmaf(b.y, xv.y, s);
      s = fmaf(b.z, xv.z, s); s = fmaf(b.w, xv.w, s);
    }
    float lin = fmaxf(s, 1e-12f);
    pv512[t] = lin * lin;
  }
  __syncthreads();

  // ---- Phase 2: MFMA GEMM, wave wv owns f-rows [128wv, 128wv+128) ----
  f32x4 acc[8];
#pragma unroll
  for (int ft = 0; ft < 8; ++ft) acc[ft] = (f32x4){0.f, 0.f, 0.f, 0.f};

  const bf16x8* bfr = (const bf16x8*)bimg;
#pragma unroll
  for (int ks = 0; ks < 4; ++ks) {
    bf16x8 xh = *(const bf16x8*)&Xf[ks * 2][lane * 8];
    bf16x8 xl = *(const bf16x8*)&Xf[ks * 2 + 1][lane * 8];
#pragma unroll
    for (int ft2 = 0; ft2 < 8; ++ft2) {
      int w8 = wv * 2 + (ft2 >> 2);
      int ftl = ft2 & 3;
      int fr = ((w8 * 4 + ftl) * 4 + ks) * 2;
      bf16x8 ah = bfr[fr * 64 + lane];
      bf16x8 al = bfr[(fr + 1) * 64 + lane];
      acc[ft2] = __builtin_amdgcn_mfma_f32_16x16x32_bf16(ah, xh, acc[ft2], 0, 0, 0);
      acc[ft2] = __builtin_amdgcn_mfma_f32_16x16x32_bf16(ah, xl, acc[ft2], 0, 0, 0);
      acc[ft2] = __builtin_amdgcn_mfma_f32_16x16x32_bf16(al, xh, acc[ft2], 0, 0, 0);
    }
  }

  // ---- Phase 3: clamp/square + cos-weighted reduce over f ----
  // C map: col = lane&15 (frame), row = (lane>>4)*4 + j (f within tile)
  float pk[5];
#pragma unroll
  for (int k = 0; k < 5; ++k) pk[k] = 0.f;

#pragma unroll
  for (int ft2 = 0; ft2 < 8; ++ft2) {
    int w8 = wv * 2 + (ft2 >> 2);
    int ftl = ft2 & 3;
#pragma unroll
    for (int j = 0; j < 4; ++j) {
      int f = w8 * 64 + ftl * 16 + ((lane >> 4) << 2) + j;
      float lin = fmaxf(acc[ft2][j], 1e-12f);
      float p = lin * lin;
      pk[0] = fmaf(W_s[0][f], p, pk[0]);
      pk[1] = fmaf(W_s[1][f], p, pk[1]);
      pk[2] = fmaf(W_s[2][f], p, pk[2]);
      pk[3] = fmaf(W_s[3][f], p, pk[3]);
      pk[4] = fmaf(W_s[4][f], p, pk[4]);
    }
  }
#pragma unroll
  for (int k = 0; k < 5; ++k) {
    float v = pk[k];
    v += __shfl_xor(v, 16);
    v += __shfl_xor(v, 32);
    if (lane < FPB) red[wv][k][lane] = v;
  }
  __syncthreads();

  // ---- Phase 4: cross-wave sum + f=512 + Levinson-Durbin (1 lane/frame) --
  if (tid < FPB) {
    const int t = tid;
    float ac[5];
#pragma unroll
    for (int k = 0; k < 5; ++k) {
      float s = red[0][k][t] + red[1][k][t] + red[2][k][t] + red[3][k][t];
      ac[k] = s + W_s[k][512] * pv512[t];
    }

    float E = ac[0];
    float k0 = ac[1] / E;
    E *= fmaxf(1.0f - k0 * k0, 1e-5f);
    float l0 = -k0;

    float a1 = ac[2] + l0 * ac[1];
    float k1 = a1 / E;
    E *= fmaxf(1.0f - k1 * k1, 1e-5f);
    float m0 = l0 - k1 * l0;
    float m1 = -k1;

    float a2 = ac[3] + m0 * ac[2] + m1 * ac[1];
    float k2 = a2 / E;
    E *= fmaxf(1.0f - k2 * k2, 1e-5f);
    float n0 = m0 - k2 * m1;
    float n1 = m1 - k2 * m0;
    float n2 = -k2;

    float a3 = ac[4] + n0 * ac[3] + n1 * ac[2] + n2 * ac[1];
    float k3 = a3 / E;
    float o0 = n0 - k3 * n2;
    float o1 = n1 - k3 * n1;
    float o2 = n2 - k3 * n0;
    float o3 = -k3;

    lp[0][t] = -o3;
    lp[1][t] = -o2;
    lp[2][t] = -o1;
    lp[3][t] = -o0;
  }
  __syncthreads();

  // ---- Phase 5: repeat-expand write, coalesced float4 ----
  // per block: 4 rows x 16 frames x 256 reps = 4096 float4
  float4* out4 = (float4*)out;
#pragma unroll
  for (int i = 0; i < 16; ++i) {
    int vid = i * BT + tid;       // 0..4095
    int j = vid >> 10;            // output row 0..3
    int rem = vid & 1023;         // float4 idx within block's row chunk
    int tl = rem >> 6;            // local frame 0..15 (wave-uniform)
    float v = lp[j][tl];
    out4[(size_t)j * (T_FRAMES * 256 / 4) + (size_t)t0 * 64 + rem] =
        make_float4(v, v, v, v);
  }
}

extern "C" void kernel_launch(void* const* d_in, const int* in_sizes, int n_in,
                              void* d_out, int out_size, void* d_ws, size_t ws_size,
                              hipStream_t stream) {
  const float* mel = (const float*)d_in[0];
  const float* B   = (const float*)d_in[1];
  const float* lag = (const float*)d_in[2];
  unsigned short* bimg = (unsigned short*)d_ws;   // 256 KB frag-ready B
  build_bimg<<<64, 256, 0, stream>>>(B, bimg);
  mel2lpc_mfma<<<T_FRAMES / FPB, BT, 0, stream>>>(mel, B, lag, bimg, (float*)d_out);
}

// Round 13
// 96.954 us; speedup vs baseline: 1.2905x; 1.2905x over previous
//
#include <hip/hip_runtime.h>

#define T_FRAMES 16384
#define N_MELS 128
#define N_FREQ 513
#define FPB 32             // frames per block
#define BT 512             // 8 waves
#define LOG2_10 3.3219280948873623f

typedef short bf16x8 __attribute__((ext_vector_type(8)));
typedef unsigned short u16x8 __attribute__((ext_vector_type(8)));
typedef float f32x4 __attribute__((ext_vector_type(4)));

__device__ __forceinline__ unsigned short f2bf(float x) {
  unsigned u = __float_as_uint(x);
  return (unsigned short)((u + 0x7FFFu + ((u >> 16) & 1u)) >> 16);
}
__device__ __forceinline__ float bf2f(unsigned short h) {
  return __uint_as_float(((unsigned)h) << 16);
}

// ---- Kernel 0: build frag-ready bf16 hi/lo image of B + W table ---------
// blocks 0..63: bimg. gid bits [w8:3][ft:2][ks:2][hl:1][l:6]; lane l of frag
// (w8,ft,ks,hl) holds B[f][k0..k0+8) bf16, f=w8*64+ft*16+(l&15),
// k0=ks*32+(l>>4)*8.  block 64: W[k][f]=lag[k]*cf*cos(2pi k f/1024) -> wimg.
__global__ __launch_bounds__(256) void build_tables(
    const float* __restrict__ B, const float* __restrict__ lag,
    unsigned short* __restrict__ img, float* __restrict__ wimg) {
  if (blockIdx.x == 64) {
    int tid = threadIdx.x;
    for (int idx = tid; idx < 5 * N_FREQ; idx += 256) {
      int k = idx / N_FREQ;
      int f = idx - k * N_FREQ;
      float cf = (f == 0 || f == N_FREQ - 1) ? (1.0f / 1024.0f) : (2.0f / 1024.0f);
      wimg[idx] = lag[k] * cf * cospif((float)(k * f) * (1.0f / 512.0f));
    }
    return;
  }
  int gid = blockIdx.x * 256 + threadIdx.x;   // 0..16383
  int l  = gid & 63;
  int hl = (gid >> 6) & 1;
  int ks = (gid >> 7) & 3;
  int ft = (gid >> 9) & 3;
  int w  = gid >> 11;
  int f  = w * 64 + ft * 16 + (l & 15);
  int k0 = ks * 32 + (l >> 4) * 8;
  const float* src = B + f * N_MELS + k0;
  u16x8 o;
#pragma unroll
  for (int j = 0; j < 8; ++j) {
    float x = src[j];
    unsigned short hi = f2bf(x);
    o[j] = hl ? f2bf(x - bf2f(hi)) : hi;
  }
  *((u16x8*)img + gid) = o;
}

// ---- Kernel A: fused MFMA GEMM + cos transform + Levinson + expand ------
// LDS overlay plan (bytes):
//   [0, 16896)      X32T float[32][132]   -- dead after frag build / f512
//     overlay:      red  float[8][5][32] at 0      (5120 B)
//                   lp   float[4][32]    at 5120   (512 B)
//   [16896, 33280)  Xf   short[16][512]
//   [33280, 43540)  W_s  float[5][513]
//   [43552, 43680)  pv512 float[32]
#define SM_X32T 0
#define SM_RED  0
#define SM_LP   5120
#define SM_XF   16896
#define SM_W    33280
#define SM_PV   43552
#define SM_SIZE 43712

__global__ __launch_bounds__(BT, 4) void mel2lpc_mfma(
    const float* __restrict__ mel,   // [128][16384]
    const float* __restrict__ B,     // [513][128] (row 512 only)
    const unsigned short* __restrict__ bimg,
    const float* __restrict__ wimg,  // [5][513] precomputed W
    float* __restrict__ out)         // [4][16384*256]
{
  __shared__ __align__(16) char smem[SM_SIZE];
  float (*X32T)[132] = (float(*)[132])(smem + SM_X32T);
  short (*Xf)[512]   = (short(*)[512])(smem + SM_XF);
  float (*W_s)[513]  = (float(*)[513])(smem + SM_W);
  float (*red)[5][32] = (float(*)[5][32])(smem + SM_RED);
  float (*lp)[32]    = (float(*)[32])(smem + SM_LP);
  float* pv512       = (float*)(smem + SM_PV);

  const int tid = threadIdx.x;
  const int lane = tid & 63;
  const int w = __builtin_amdgcn_readfirstlane(tid >> 6);
  const int t0 = blockIdx.x * FPB;

  // ---- Phase 0: issue mel loads first (hide HBM latency under W load) ----
  float mv[8];
#pragma unroll
  for (int r = 0; r < 8; ++r) {
    int idx = r * BT + tid;    // 0..4095
    int t = idx & 31;
    int m = idx >> 5;
    mv[r] = mel[m * T_FRAMES + t0 + t];
  }
  // W table from global (L2-hot, precomputed)
  for (int idx = tid; idx < 5 * N_FREQ; idx += BT) {
    ((float*)W_s)[(idx / N_FREQ) * 513 + (idx % N_FREQ)] = wimg[idx];
  }
#pragma unroll
  for (int r = 0; r < 8; ++r) {
    int idx = r * BT + tid;
    int t = idx & 31;
    int m = idx >> 5;
    X32T[t][m] = exp2f(mv[r] * LOG2_10);
  }
  __syncthreads();

  // ---- Phase 1a: f=512 row power (before X32T dies) ----
  if (tid < FPB) {
    const int t = tid;
    float s = 0.f;
    const float4* __restrict__ B512 = (const float4*)(B + 512 * N_MELS);
#pragma unroll
    for (int mi = 0; mi < 32; ++mi) {
      float4 b = B512[mi];
      float4 xv = *(const float4*)&X32T[t][mi * 4];
      s = fmaf(b.x, xv.x, s); s = fmaf(b.y, xv.y, s);
      s = fmaf(b.z, xv.z, s); s = fmaf(b.w, xv.w, s);
    }
    float lin = fmaxf(s, 1e-12f);
    pv512[t] = lin * lin;
  }
  // ---- Phase 1b: build X frags (wave w builds frag-pair w) ----
  {
    int tt = w >> 2, ks = w & 3;           // tt in {0,1}
    int t = tt * 16 + (lane & 15);
    int k0 = ks * 32 + (lane >> 4) * 8;
    float4 a0 = *(const float4*)&X32T[t][k0];
    float4 a1 = *(const float4*)&X32T[t][k0 + 4];
    float xs[8] = {a0.x, a0.y, a0.z, a0.w, a1.x, a1.y, a1.z, a1.w};
    u16x8 vh, vl;
#pragma unroll
    for (int j = 0; j < 8; ++j) {
      unsigned short hi = f2bf(xs[j]);
      vh[j] = hi;
      vl[j] = f2bf(xs[j] - bf2f(hi));
    }
    *(u16x8*)&Xf[w * 2][lane * 8] = vh;
    *(u16x8*)&Xf[w * 2 + 1][lane * 8] = vl;
  }
  __syncthreads();   // X32T dead from here; red/lp overlay becomes legal

  // ---- Phase 2: MFMA GEMM, wave w owns f-rows [64w, 64w+64) x 32 t ----
  f32x4 acc[4][2];
#pragma unroll
  for (int ft = 0; ft < 4; ++ft)
#pragma unroll
    for (int tt = 0; tt < 2; ++tt) acc[ft][tt] = (f32x4){0.f, 0.f, 0.f, 0.f};

  const bf16x8* bfr = (const bf16x8*)bimg;
#pragma unroll
  for (int ks = 0; ks < 4; ++ks) {
    bf16x8 xh0 = *(const bf16x8*)&Xf[(0 * 4 + ks) * 2][lane * 8];
    bf16x8 xl0 = *(const bf16x8*)&Xf[(0 * 4 + ks) * 2 + 1][lane * 8];
    bf16x8 xh1 = *(const bf16x8*)&Xf[(1 * 4 + ks) * 2][lane * 8];
    bf16x8 xl1 = *(const bf16x8*)&Xf[(1 * 4 + ks) * 2 + 1][lane * 8];
#pragma unroll
    for (int ft = 0; ft < 4; ++ft) {
      int fr = ((w * 4 + ft) * 4 + ks) * 2;
      bf16x8 ah = bfr[fr * 64 + lane];
      bf16x8 al = bfr[(fr + 1) * 64 + lane];
      acc[ft][0] = __builtin_amdgcn_mfma_f32_16x16x32_bf16(ah, xh0, acc[ft][0], 0, 0, 0);
      acc[ft][0] = __builtin_amdgcn_mfma_f32_16x16x32_bf16(ah, xl0, acc[ft][0], 0, 0, 0);
      acc[ft][0] = __builtin_amdgcn_mfma_f32_16x16x32_bf16(al, xh0, acc[ft][0], 0, 0, 0);
      acc[ft][1] = __builtin_amdgcn_mfma_f32_16x16x32_bf16(ah, xh1, acc[ft][1], 0, 0, 0);
      acc[ft][1] = __builtin_amdgcn_mfma_f32_16x16x32_bf16(ah, xl1, acc[ft][1], 0, 0, 0);
      acc[ft][1] = __builtin_amdgcn_mfma_f32_16x16x32_bf16(al, xh1, acc[ft][1], 0, 0, 0);
    }
  }

  // ---- Phase 3: clamp/square + cos-weighted reduce over f ----
  // C map: col = lane&15 (t within tt tile), row = (lane>>4)*4 + j (f)
  float pk[5][2];
#pragma unroll
  for (int k = 0; k < 5; ++k)
#pragma unroll
    for (int tt = 0; tt < 2; ++tt) pk[k][tt] = 0.f;

#pragma unroll
  for (int ft = 0; ft < 4; ++ft) {
#pragma unroll
    for (int j = 0; j < 4; ++j) {
      int f = w * 64 + ft * 16 + ((lane >> 4) << 2) + j;
      float w0 = W_s[0][f], w1 = W_s[1][f], w2 = W_s[2][f];
      float w3 = W_s[3][f], w4 = W_s[4][f];
#pragma unroll
      for (int tt = 0; tt < 2; ++tt) {
        float lin = fmaxf(acc[ft][tt][j], 1e-12f);
        float p = lin * lin;
        pk[0][tt] = fmaf(w0, p, pk[0][tt]);
        pk[1][tt] = fmaf(w1, p, pk[1][tt]);
        pk[2][tt] = fmaf(w2, p, pk[2][tt]);
        pk[3][tt] = fmaf(w3, p, pk[3][tt]);
        pk[4][tt] = fmaf(w4, p, pk[4][tt]);
      }
    }
  }
#pragma unroll
  for (int k = 0; k < 5; ++k)
#pragma unroll
    for (int tt = 0; tt < 2; ++tt) {
      float v = pk[k][tt];
      v += __shfl_xor(v, 16);
      v += __shfl_xor(v, 32);
      if (lane < 16) red[w][k][tt * 16 + lane] = v;
    }
  __syncthreads();

  // ---- Phase 4: cross-wave sum + f=512 + Levinson-Durbin (1 lane/frame) --
  if (tid < FPB) {
    const int t = tid;
    float ac[5];
#pragma unroll
    for (int k = 0; k < 5; ++k) {
      float s = 0.f;
#pragma unroll
      for (int w2 = 0; w2 < 8; ++w2) s += red[w2][k][t];
      ac[k] = s + W_s[k][512] * pv512[t];
    }

    float E = ac[0];
    float k0 = ac[1] / E;
    E *= fmaxf(1.0f - k0 * k0, 1e-5f);
    float l0 = -k0;

    float a1 = ac[2] + l0 * ac[1];
    float k1 = a1 / E;
    E *= fmaxf(1.0f - k1 * k1, 1e-5f);
    float m0 = l0 - k1 * l0;
    float m1 = -k1;

    float a2 = ac[3] + m0 * ac[2] + m1 * ac[1];
    float k2 = a2 / E;
    E *= fmaxf(1.0f - k2 * k2, 1e-5f);
    float n0 = m0 - k2 * m1;
    float n1 = m1 - k2 * m0;
    float n2 = -k2;

    float a3 = ac[4] + n0 * ac[3] + n1 * ac[2] + n2 * ac[1];
    float k3 = a3 / E;
    float o0 = n0 - k3 * n2;
    float o1 = n1 - k3 * n1;
    float o2 = n2 - k3 * n0;
    float o3 = -k3;

    lp[0][t] = -o3;
    lp[1][t] = -o2;
    lp[2][t] = -o1;
    lp[3][t] = -o0;
  }
  __syncthreads();

  // ---- Phase 5: repeat-expand write, coalesced float4 ----
  // per block: 4 rows x 32 frames x 256 reps = 8192 float4
  float4* out4 = (float4*)out;
#pragma unroll
  for (int i = 0; i < 16; ++i) {
    int vid = i * BT + tid;       // 0..8191
    int j = vid >> 11;            // output row 0..3
    int rem = vid & 2047;         // float4 idx within block's row chunk
    int tl = rem >> 6;            // local frame 0..31 (wave-uniform)
    float v = lp[j][tl];
    out4[(size_t)j * (T_FRAMES * 256 / 4) + (size_t)t0 * 64 + rem] =
        make_float4(v, v, v, v);
  }
}

extern "C" void kernel_launch(void* const* d_in, const int* in_sizes, int n_in,
                              void* d_out, int out_size, void* d_ws, size_t ws_size,
                              hipStream_t stream) {
  const float* mel = (const float*)d_in[0];
  const float* B   = (const float*)d_in[1];
  const float* lag = (const float*)d_in[2];
  unsigned short* bimg = (unsigned short*)d_ws;          // 256 KB frag-ready B
  float* wimg = (float*)((char*)d_ws + 512 * 1024);      // 10.3 KB W table
  build_tables<<<65, 256, 0, stream>>>(B, lag, bimg, wimg);
  mel2lpc_mfma<<<T_FRAMES / FPB, BT, 0, stream>>>(mel, B, bimg, wimg, (float*)d_out);
}